// Round 19
// baseline (146.113 us; speedup 1.0000x reference)
//
#include <hip/hip_runtime.h>

// SAdapter v19: v18 + barrier reduction (4 -> 2).
//  - Phase 0 inits only the 480 BORDER cells of TS/PS (disjoint from phase A's
//    interior writes) -> no barrier before A; global loads issue immediately.
//  - C2 fused into D per-wave: wave wv computes its own ZH slice
//    [392wv, 392wv+392) from PS (in-wave LDS ordering, no __syncthreads);
//    waves decouple after the BC barrier.
// Rest identical to v18 (140.98 us): f16 dot2 A/D, NT stores, 18432 B LDS.

#define DIMD 192
#define IMGS 37824           // 197*192
#define NIMG 2048

typedef __fp16 half2_t __attribute__((ext_vector_type(2)));
typedef float vfloat4 __attribute__((ext_vector_type(4)));

__device__ __forceinline__ half2_t u2h(unsigned u) {
    union { unsigned u; half2_t h; } cv; cv.u = u; return cv.h;
}
__device__ __forceinline__ unsigned h2u(half2_t h) {
    union { half2_t h; unsigned u; } cv; cv.h = h; return cv.u;
}

// ---- K0: pack W1 (8x192) and hist_w (192x8) into f16 pairs ----
__global__ void k0_pack(const float* __restrict__ W1,
                        const float* __restrict__ hist_w,
                        unsigned* __restrict__ wsA,
                        unsigned* __restrict__ wsD)
{
    int f = threadIdx.x + blockIdx.x * 256;
    if (f < 768) {
        wsA[f] = h2u(__builtin_amdgcn_cvt_pkrtz(W1[2*f], W1[2*f+1]));
        wsD[f] = h2u(__builtin_amdgcn_cvt_pkrtz(hist_w[2*f], hist_w[2*f+1]));
    }
}

__launch_bounds__(256)
__global__ void sadapter_kernel(
    const float* __restrict__ x,
    const float* __restrict__ b1,
    const float* __restrict__ conv1_w,
    const float* __restrict__ conv1_b,
    const float* __restrict__ cdc_w,
    const float* __restrict__ wc1,
    const float* __restrict__ wc2,
    const unsigned* __restrict__ wsA,
    const unsigned* __restrict__ wsD,
    const float* __restrict__ hist_b,
    float* __restrict__ out)
{
    __shared__ float smem[4608];   // 18432 B
    float* TS  = smem;             // [8][16][16] padded t (border 0); dead after BC
    float* ZH  = smem;             // [1568] flat z_hist (c*196+hw), overlays TS
    float* PS  = smem + 2048;      // [8][16][16] padded P (border 1)
    float* WB2 = smem + 4096;      // [64][8] packed small weights

    const int tid = threadIdx.x;
    const float* xb   = x   + (size_t)blockIdx.x * IMGS;
    float*       outb = out + (size_t)blockIdx.x * IMGS;

    // ---- Phase 0 (NO barrier): border-only init, WB2 pack, class token ----
    // Border cells (60/channel x 8 = 480) are disjoint from A's interior writes.
    for (int b = tid; b < 480; b += 256) {
        int c = b / 60, r = b - c * 60;
        int h, w;
        if (r < 16)      { h = 0;      w = r;      }
        else if (r < 32) { h = 15;     w = r - 16; }
        else if (r < 46) { h = r - 31; w = 0;      }
        else             { h = r - 45; w = 15;     }
        TS[c * 256 + h * 16 + w] = 0.f;
        PS[c * 256 + h * 16 + w] = 1.f;
    }
    if (tid < 64) {
        const float* c5 = cdc_w + tid * 5;                 // cdc_w (8,8,1,5), tid=o*8+i
        float k0 = c5[0], k1 = c5[1], k2 = c5[2], k3 = c5[3], k4 = c5[4];
        float kd = k0 + k1 + k2 + k3 + k4;
        float* wp = WB2 + tid * 8;
        wp[0] = conv1_w[tid] + k2 - 0.7f * kd;  // center: 1x1 + cdc-center - theta*diff
        wp[1] = k0; wp[2] = k1; wp[3] = k3; wp[4] = k4;    // up,left,right,down
        wp[5] = wc1[tid];
        wp[6] = wc2[tid];
        wp[7] = 0.f;
    }

    // ---- Phase A: t[n,c] = tok[n,:] @ W1[c,:] + b1[c]  (f16 dot2 path) ----
    if (tid < 196) {
        const float4* rowp = (const float4*)(xb + DIMD + tid * DIMD);
        float acc[8];
        #pragma unroll
        for (int c = 0; c < 8; ++c) acc[c] = b1[c];        // uniform -> s_load
        #pragma unroll
        for (int blk = 0; blk < 6; ++blk) {                // 6 batches of 32 dims
            float4 tv[8];
            #pragma unroll
            for (int u = 0; u < 8; ++u) tv[u] = rowp[blk * 8 + u];
            half2_t tp16[16];
            #pragma unroll
            for (int u = 0; u < 8; ++u) {
                tp16[2*u]   = __builtin_amdgcn_cvt_pkrtz(tv[u].x, tv[u].y);
                tp16[2*u+1] = __builtin_amdgcn_cvt_pkrtz(tv[u].z, tv[u].w);
            }
            #pragma unroll
            for (int c = 0; c < 8; ++c) {
                const unsigned* wp = wsA + c * 96 + blk * 16;   // uniform -> s_load
                #pragma unroll
                for (int j = 0; j < 16; ++j)
                    acc[c] = __builtin_amdgcn_fdot2(tp16[j], u2h(wp[j]), acc[c], false);
            }
        }
        int h = tid / 14, w = tid - h * 14;
        float* tp = TS + (h + 1) * 16 + (w + 1);
        #pragma unroll
        for (int c = 0; c < 8; ++c) tp[c * 256] = acc[c];
    } else if (tid >= 208) {
        // class token passthrough, nontemporal (write-once data)
        const vfloat4 v = ((const vfloat4*)xb)[tid - 208];
        __builtin_nontemporal_store(v, ((vfloat4*)outb) + (tid - 208));
    }
    __syncthreads();   // barrier 1: TS (borders + interior) complete

    // ---- Phase BC: z_star in regs -> mu/gamma -> P = exp(-(g*(z-mu))^2) ----
    if (tid < 196) {
        int h = tid / 14, w = tid - h * 14;
        const float* tp = TS + (h + 1) * 16 + (w + 1);
        float zv[8];
        #pragma unroll
        for (int c = 0; c < 8; ++c) zv[c] = conv1_b[c];    // uniform -> s_load
        #pragma unroll
        for (int i = 0; i < 8; ++i) {
            float t0 = tp[i * 256];
            float tu = tp[i * 256 - 16];
            float td = tp[i * 256 + 16];
            float tl = tp[i * 256 - 1];
            float tr = tp[i * 256 + 1];
            #pragma unroll
            for (int c = 0; c < 8; ++c) {
                const float* wp = WB2 + (c * 8 + i) * 8;   // broadcast b128 + b32
                float4 wv = *(const float4*)wp;
                float wd = wp[4];
                zv[c] += wv.x * t0 + wv.y * tu + wv.z * tl + wv.w * tr + wd * td;
            }
        }
        float* pp = PS + (h + 1) * 16 + (w + 1);
        #pragma unroll
        for (int c = 0; c < 8; ++c) {
            float mu = 0.f, ga = 0.f;
            #pragma unroll
            for (int i = 0; i < 8; ++i) {
                const float* wp = WB2 + (c * 8 + i) * 8;
                mu += wp[5] * zv[i];
                ga += wp[6] * zv[i];
            }
            float e = ga * (zv[c] - mu);
            pp[c * 256] = __expf(-e * e);
        }
    }
    __syncthreads();   // barrier 2: PS complete; TS now dead

    // ---- Fused C2+D, per-wave (no further barriers) ----
    const int l  = tid & 63;          // lane
    const int wv = tid >> 6;          // wave 0..3
    const int ls = (l < 48) ? l : 47; // clamp for safe hoisted loads
    const uint4  w0  = *(const uint4*)(wsD + ls * 16);
    const uint4  w1  = *(const uint4*)(wsD + ls * 16 + 4);
    const uint4  w2  = *(const uint4*)(wsD + ls * 16 + 8);
    const uint4  w3  = *(const uint4*)(wsD + ls * 16 + 12);
    const float4 hb4 = *(const float4*)(hist_b + ls * 4);

    // C2 slice: wave wv computes ZH[392wv .. 392wv+392) = channels 2wv,2wv+1
    {
        const int base = wv * 392;
        #pragma unroll
        for (int it = 0; it < 7; ++it) {
            int q = it * 64 + l;
            if (q < 392) {
                int c  = 2 * wv + (q >= 196);
                int hw = (q >= 196) ? q - 196 : q;
                int h = hw / 14, w = hw - (hw / 14) * 14;
                const float* pr = PS + c * 256 + h * 16 + w;   // top-left of 3x3
                float s9 = pr[0]  + pr[1]  + pr[2]
                         + pr[16] + pr[17] + pr[18]
                         + pr[32] + pr[33] + pr[34];
                ZH[base + q] = s9 * (1.f / 9.f);
            }
        }
    }
    // in-wave LDS write->read: program order + lgkmcnt, no __syncthreads needed

    // D: wave wv -> rows 49wv..+48; lane l<48 -> dims 4l..4l+3; float4 NT stores
    if (l < 48) {
        float* oy = outb + DIMD;
        const int n2beg = wv * 49;
        #pragma unroll 2
        for (int k = 0; k < 49; ++k) {
            const int n2 = n2beg + k;
            const float4 z0 = *(const float4*)(ZH + n2 * 8);     // broadcast b128
            const float4 z1 = *(const float4*)(ZH + n2 * 8 + 4); // broadcast b128
            half2_t zp0 = __builtin_amdgcn_cvt_pkrtz(z0.x, z0.y);
            half2_t zp1 = __builtin_amdgcn_cvt_pkrtz(z0.z, z0.w);
            half2_t zp2 = __builtin_amdgcn_cvt_pkrtz(z1.x, z1.y);
            half2_t zp3 = __builtin_amdgcn_cvt_pkrtz(z1.z, z1.w);
            vfloat4 a;
            float t;
            t = hb4.x;
            t = __builtin_amdgcn_fdot2(zp0, u2h(w0.x), t, false);
            t = __builtin_amdgcn_fdot2(zp1, u2h(w0.y), t, false);
            t = __builtin_amdgcn_fdot2(zp2, u2h(w0.z), t, false);
            t = __builtin_amdgcn_fdot2(zp3, u2h(w0.w), t, false);
            a.x = t;
            t = hb4.y;
            t = __builtin_amdgcn_fdot2(zp0, u2h(w1.x), t, false);
            t = __builtin_amdgcn_fdot2(zp1, u2h(w1.y), t, false);
            t = __builtin_amdgcn_fdot2(zp2, u2h(w1.z), t, false);
            t = __builtin_amdgcn_fdot2(zp3, u2h(w1.w), t, false);
            a.y = t;
            t = hb4.z;
            t = __builtin_amdgcn_fdot2(zp0, u2h(w2.x), t, false);
            t = __builtin_amdgcn_fdot2(zp1, u2h(w2.y), t, false);
            t = __builtin_amdgcn_fdot2(zp2, u2h(w2.z), t, false);
            t = __builtin_amdgcn_fdot2(zp3, u2h(w2.w), t, false);
            a.z = t;
            t = hb4.w;
            t = __builtin_amdgcn_fdot2(zp0, u2h(w3.x), t, false);
            t = __builtin_amdgcn_fdot2(zp1, u2h(w3.y), t, false);
            t = __builtin_amdgcn_fdot2(zp2, u2h(w3.z), t, false);
            t = __builtin_amdgcn_fdot2(zp3, u2h(w3.w), t, false);
            a.w = t;
            __builtin_nontemporal_store(a, (vfloat4*)(oy + n2 * DIMD) + l);
        }
    }
}

// ---------------- fused fp32 fallback (v9, only if ws too small) ----------------
__launch_bounds__(256)
__global__ void sadapter_fused(
    const float* __restrict__ x,
    const float* __restrict__ W1,
    const float* __restrict__ b1,
    const float* __restrict__ conv1_w,
    const float* __restrict__ conv1_b,
    const float* __restrict__ cdc_w,
    const float* __restrict__ wc1,
    const float* __restrict__ wc2,
    const float* __restrict__ hist_w,
    const float* __restrict__ hist_b,
    float* __restrict__ out)
{
    __shared__ float smem[4608];
    float* TS  = smem;
    float* ZH  = smem;
    float* PS  = smem + 2048;
    float* WB2 = smem + 4096;
    const int tid = threadIdx.x;
    const float* xb   = x   + (size_t)blockIdx.x * IMGS;
    float*       outb = out + (size_t)blockIdx.x * IMGS;

    {
        float4 z4 = make_float4(0.f,0.f,0.f,0.f), o4 = make_float4(1.f,1.f,1.f,1.f);
        ((float4*)TS)[tid] = z4; ((float4*)TS)[tid+256] = z4;
        ((float4*)PS)[tid] = o4; ((float4*)PS)[tid+256] = o4;
    }
    if (tid < 64) {
        const float* c5 = cdc_w + tid * 5;
        float k0=c5[0],k1=c5[1],k2=c5[2],k3=c5[3],k4=c5[4];
        float kd = k0+k1+k2+k3+k4;
        float* wp = WB2 + tid*8;
        wp[0]=conv1_w[tid]+k2-0.7f*kd; wp[1]=k0; wp[2]=k1; wp[3]=k3; wp[4]=k4;
        wp[5]=wc1[tid]; wp[6]=wc2[tid]; wp[7]=0.f;
    }
    __syncthreads();
    if (tid < 196) {
        const float4* rowp = (const float4*)(xb + DIMD + tid * DIMD);
        float acc[8];
        #pragma unroll
        for (int c=0;c<8;++c) acc[c]=b1[c];
        #pragma unroll
        for (int blk=0; blk<6; ++blk) {
            float4 tv[8];
            #pragma unroll
            for (int u=0;u<8;++u) tv[u]=rowp[blk*8+u];
            #pragma unroll
            for (int c=0;c<8;++c) {
                const float* wrow = W1 + c*DIMD + blk*32;
                #pragma unroll
                for (int u=0;u<8;++u)
                    acc[c] += tv[u].x*wrow[u*4+0]+tv[u].y*wrow[u*4+1]
                            + tv[u].z*wrow[u*4+2]+tv[u].w*wrow[u*4+3];
            }
        }
        int h=tid/14, w=tid-h*14;
        float* tp = TS + (h+1)*16 + (w+1);
        #pragma unroll
        for (int c=0;c<8;++c) tp[c*256]=acc[c];
    } else if (tid >= 208) {
        ((float4*)outb)[tid-208] = ((const float4*)xb)[tid-208];
    }
    __syncthreads();
    if (tid < 196) {
        int h=tid/14, w=tid-h*14;
        const float* tp = TS + (h+1)*16 + (w+1);
        float zv[8];
        #pragma unroll
        for (int c=0;c<8;++c) zv[c]=conv1_b[c];
        #pragma unroll
        for (int i=0;i<8;++i) {
            float t0=tp[i*256], tu=tp[i*256-16], td=tp[i*256+16], tl=tp[i*256-1], tr=tp[i*256+1];
            #pragma unroll
            for (int c=0;c<8;++c) {
                const float* wp = WB2 + (c*8+i)*8;
                float4 wv = *(const float4*)wp;
                zv[c] += wv.x*t0 + wv.y*tu + wv.z*tl + wv.w*tr + wp[4]*td;
            }
        }
        float* pp = PS + (h+1)*16 + (w+1);
        #pragma unroll
        for (int c=0;c<8;++c) {
            float mu=0.f, ga=0.f;
            #pragma unroll
            for (int i=0;i<8;++i) {
                const float* wp = WB2 + (c*8+i)*8;
                mu += wp[5]*zv[i]; ga += wp[6]*zv[i];
            }
            float e = ga*(zv[c]-mu);
            pp[c*256] = __expf(-e*e);
        }
    }
    __syncthreads();
    const int l  = tid & 63;
    const int wv = tid >> 6;
    const float4 ha0 = *(const float4*)(hist_w + l * 8);
    const float4 ha1 = *(const float4*)(hist_w + l * 8 + 4);
    const float4 hb0 = *(const float4*)(hist_w + (l + 64) * 8);
    const float4 hb1 = *(const float4*)(hist_w + (l + 64) * 8 + 4);
    const float4 hc0 = *(const float4*)(hist_w + (l + 128) * 8);
    const float4 hc1 = *(const float4*)(hist_w + (l + 128) * 8 + 4);
    const float  ba  = hist_b[l];
    const float  bb  = hist_b[l + 64];
    const float  bc_ = hist_b[l + 128];
    if (tid < 196) {
        int h=tid/14, w=tid-h*14;
        const float* pb = PS + h*16 + w;
        #pragma unroll
        for (int c=0;c<8;++c) {
            const float* pr = pb + c*256;
            float s9 = pr[0]+pr[1]+pr[2]+pr[16]+pr[17]+pr[18]+pr[32]+pr[33]+pr[34];
            ZH[c*196+tid] = s9*(1.f/9.f);
        }
    }
    __syncthreads();
    {
        float* oy = outb + DIMD;
        const int n2beg = wv * 49;
        #pragma unroll 2
        for (int k = 0; k < 49; ++k) {
            const int n2 = n2beg + k;
            const float4 z0 = *(const float4*)(ZH + n2 * 8);
            const float4 z1 = *(const float4*)(ZH + n2 * 8 + 4);
            float a0 = ba + z0.x*ha0.x + z0.y*ha0.y + z0.z*ha0.z + z0.w*ha0.w
                          + z1.x*ha1.x + z1.y*ha1.y + z1.z*ha1.z + z1.w*ha1.w;
            float a1 = bb + z0.x*hb0.x + z0.y*hb0.y + z0.z*hb0.z + z0.w*hb0.w
                          + z1.x*hb1.x + z1.y*hb1.y + z1.z*hb1.z + z1.w*hb1.w;
            float a2 = bc_+ z0.x*hc0.x + z0.y*hc0.y + z0.z*hc0.z + z0.w*hc0.w
                          + z1.x*hc1.x + z1.y*hc1.y + z1.z*hc1.z + z1.w*hc1.w;
            float* orow = oy + n2 * DIMD;
            orow[l]       = a0;
            orow[l + 64]  = a1;
            orow[l + 128] = a2;
        }
    }
}

extern "C" void kernel_launch(void* const* d_in, const int* in_sizes, int n_in,
                              void* d_out, int out_size, void* d_ws, size_t ws_size,
                              hipStream_t stream)
{
    const float* x       = (const float*)d_in[0];
    const float* W1      = (const float*)d_in[1];
    const float* b1      = (const float*)d_in[2];
    const float* conv1_w = (const float*)d_in[3];
    const float* conv1_b = (const float*)d_in[4];
    const float* cdc_w   = (const float*)d_in[5];
    const float* wc1     = (const float*)d_in[6];
    const float* wc2     = (const float*)d_in[7];
    const float* hist_w  = (const float*)d_in[8];
    const float* hist_b  = (const float*)d_in[9];
    float* out = (float*)d_out;

    const size_t need = 2 * 768 * sizeof(unsigned);   // 6 KB
    if (ws_size >= need) {
        unsigned* wsA = (unsigned*)d_ws;
        unsigned* wsD = wsA + 768;
        k0_pack<<<3, 256, 0, stream>>>(W1, hist_w, wsA, wsD);
        sadapter_kernel<<<NIMG, 256, 0, stream>>>(
            x, b1, conv1_w, conv1_b, cdc_w, wc1, wc2, wsA, wsD, hist_b, out);
    } else {
        sadapter_fused<<<NIMG, 256, 0, stream>>>(
            x, W1, b1, conv1_w, conv1_b, cdc_w, wc1, wc2, hist_w, hist_b, out);
    }
}

// Round 20
// 139.201 us; speedup vs baseline: 1.0496x; 1.0496x over previous
//
#include <hip/hip_runtime.h>

// SAdapter v20 = v18 (champion, 140.98 us) reverted after v19's barrier-
// reduction regression (146.1: serial border-init delayed A's loads; fused
// C2 raised bank conflicts 1.73M->2.04M).
// Structure: one block/image, f16 dot2 A/D GEMMs, fp32 BC/C2, NT stores,
// float4 NT phase-D stores, 18432 B LDS, 4 barriers, no launch-bound caps.

#define DIMD 192
#define IMGS 37824           // 197*192
#define NIMG 2048

typedef __fp16 half2_t __attribute__((ext_vector_type(2)));
typedef float vfloat4 __attribute__((ext_vector_type(4)));

__device__ __forceinline__ half2_t u2h(unsigned u) {
    union { unsigned u; half2_t h; } cv; cv.u = u; return cv.h;
}
__device__ __forceinline__ unsigned h2u(half2_t h) {
    union { half2_t h; unsigned u; } cv; cv.h = h; return cv.u;
}

// ---- K0: pack W1 (8x192) and hist_w (192x8) into f16 pairs ----
__global__ void k0_pack(const float* __restrict__ W1,
                        const float* __restrict__ hist_w,
                        unsigned* __restrict__ wsA,
                        unsigned* __restrict__ wsD)
{
    int f = threadIdx.x + blockIdx.x * 256;
    if (f < 768) {
        wsA[f] = h2u(__builtin_amdgcn_cvt_pkrtz(W1[2*f], W1[2*f+1]));
        wsD[f] = h2u(__builtin_amdgcn_cvt_pkrtz(hist_w[2*f], hist_w[2*f+1]));
    }
}

__launch_bounds__(256)
__global__ void sadapter_kernel(
    const float* __restrict__ x,
    const float* __restrict__ b1,
    const float* __restrict__ conv1_w,
    const float* __restrict__ conv1_b,
    const float* __restrict__ cdc_w,
    const float* __restrict__ wc1,
    const float* __restrict__ wc2,
    const unsigned* __restrict__ wsA,
    const unsigned* __restrict__ wsD,
    const float* __restrict__ hist_b,
    float* __restrict__ out)
{
    __shared__ float smem[4608];   // 18432 B
    float* TS  = smem;             // [8][16][16] padded t (border 0); dead after BC
    float* ZH  = smem;             // [1568] flat z_hist (c*196+hw), overlays TS
    float* PS  = smem + 2048;      // [8][16][16] padded P (border 1)
    float* WB2 = smem + 4096;      // [64][8] packed small weights

    const int tid = threadIdx.x;
    const float* xb   = x   + (size_t)blockIdx.x * IMGS;
    float*       outb = out + (size_t)blockIdx.x * IMGS;

    // ---- Phase 0: init borders, pack weights ----
    {
        float4 z4 = make_float4(0.f, 0.f, 0.f, 0.f);
        float4 o4 = make_float4(1.f, 1.f, 1.f, 1.f);
        ((float4*)TS)[tid]       = z4;
        ((float4*)TS)[tid + 256] = z4;
        ((float4*)PS)[tid]       = o4;
        ((float4*)PS)[tid + 256] = o4;
    }
    if (tid < 64) {
        const float* c5 = cdc_w + tid * 5;                 // cdc_w (8,8,1,5), tid=o*8+i
        float k0 = c5[0], k1 = c5[1], k2 = c5[2], k3 = c5[3], k4 = c5[4];
        float kd = k0 + k1 + k2 + k3 + k4;
        float* wp = WB2 + tid * 8;
        wp[0] = conv1_w[tid] + k2 - 0.7f * kd;  // center: 1x1 + cdc-center - theta*diff
        wp[1] = k0; wp[2] = k1; wp[3] = k3; wp[4] = k4;    // up,left,right,down
        wp[5] = wc1[tid];
        wp[6] = wc2[tid];
        wp[7] = 0.f;
    }
    __syncthreads();

    // ---- Phase A: t[n,c] = tok[n,:] @ W1[c,:] + b1[c]  (f16 dot2 path) ----
    if (tid < 196) {
        const float4* rowp = (const float4*)(xb + DIMD + tid * DIMD);
        float acc[8];
        #pragma unroll
        for (int c = 0; c < 8; ++c) acc[c] = b1[c];        // uniform -> s_load
        #pragma unroll
        for (int blk = 0; blk < 6; ++blk) {                // 6 batches of 32 dims
            float4 tv[8];
            #pragma unroll
            for (int u = 0; u < 8; ++u) tv[u] = rowp[blk * 8 + u];
            half2_t tp16[16];
            #pragma unroll
            for (int u = 0; u < 8; ++u) {
                tp16[2*u]   = __builtin_amdgcn_cvt_pkrtz(tv[u].x, tv[u].y);
                tp16[2*u+1] = __builtin_amdgcn_cvt_pkrtz(tv[u].z, tv[u].w);
            }
            #pragma unroll
            for (int c = 0; c < 8; ++c) {
                const unsigned* wp = wsA + c * 96 + blk * 16;   // uniform -> s_load
                #pragma unroll
                for (int j = 0; j < 16; ++j)
                    acc[c] = __builtin_amdgcn_fdot2(tp16[j], u2h(wp[j]), acc[c], false);
            }
        }
        int h = tid / 14, w = tid - h * 14;
        float* tp = TS + (h + 1) * 16 + (w + 1);
        #pragma unroll
        for (int c = 0; c < 8; ++c) tp[c * 256] = acc[c];
    } else if (tid >= 208) {
        // class token passthrough, nontemporal (write-once data)
        const vfloat4 v = ((const vfloat4*)xb)[tid - 208];
        __builtin_nontemporal_store(v, ((vfloat4*)outb) + (tid - 208));
    }
    __syncthreads();

    // ---- Phase BC: z_star in regs -> mu/gamma -> P = exp(-(g*(z-mu))^2) ----
    if (tid < 196) {
        int h = tid / 14, w = tid - h * 14;
        const float* tp = TS + (h + 1) * 16 + (w + 1);
        float zv[8];
        #pragma unroll
        for (int c = 0; c < 8; ++c) zv[c] = conv1_b[c];    // uniform -> s_load
        #pragma unroll
        for (int i = 0; i < 8; ++i) {
            float t0 = tp[i * 256];
            float tu = tp[i * 256 - 16];
            float td = tp[i * 256 + 16];
            float tl = tp[i * 256 - 1];
            float tr = tp[i * 256 + 1];
            #pragma unroll
            for (int c = 0; c < 8; ++c) {
                const float* wp = WB2 + (c * 8 + i) * 8;   // broadcast b128 + b32
                float4 wv = *(const float4*)wp;
                float wd = wp[4];
                zv[c] += wv.x * t0 + wv.y * tu + wv.z * tl + wv.w * tr + wd * td;
            }
        }
        float* pp = PS + (h + 1) * 16 + (w + 1);
        #pragma unroll
        for (int c = 0; c < 8; ++c) {
            float mu = 0.f, ga = 0.f;
            #pragma unroll
            for (int i = 0; i < 8; ++i) {
                const float* wp = WB2 + (c * 8 + i) * 8;
                mu += wp[5] * zv[i];
                ga += wp[6] * zv[i];
            }
            float e = ga * (zv[c] - mu);
            pp[c * 256] = __expf(-e * e);
        }
    }
    __syncthreads();

    // ---- Phase D weights (hoisted above C2 to hide latency):
    //      lane l<48 owns dims 4l..4l+3 -> 16 contiguous packed pairs ----
    const int l  = tid & 63;          // lane
    const int wv = tid >> 6;          // wave 0..3
    const int ls = (l < 48) ? l : 47; // clamp for safe OOB-free hoisted loads
    const uint4  w0  = *(const uint4*)(wsD + ls * 16);
    const uint4  w1  = *(const uint4*)(wsD + ls * 16 + 4);
    const uint4  w2  = *(const uint4*)(wsD + ls * 16 + 8);
    const uint4  w3  = *(const uint4*)(wsD + ls * 16 + 12);
    const float4 hb4 = *(const float4*)(hist_b + ls * 4);

    // ---- Phase C2: z_hist = 3x3 box sum / 9, flat (c*196+hw) into ZH ----
    if (tid < 196) {
        int h = tid / 14, w = tid - h * 14;
        const float* pb = PS + h * 16 + w;    // top-left of 3x3 window (padded coords)
        #pragma unroll
        for (int c = 0; c < 8; ++c) {
            const float* pr = pb + c * 256;
            float s9 = pr[0]  + pr[1]  + pr[2]
                     + pr[16] + pr[17] + pr[18]
                     + pr[32] + pr[33] + pr[34];
            ZH[c * 196 + tid] = s9 * (1.f / 9.f);
        }
    }
    __syncthreads();

    // ---- Phase D: wave wv -> rows 49wv..+48; lane l<48 -> dims 4l..4l+3.
    //      One float4 NT store per row (768 B/wave/instruction). ----
    if (l < 48) {
        float* oy = outb + DIMD;
        const int n2beg = wv * 49;
        #pragma unroll 2
        for (int k = 0; k < 49; ++k) {
            const int n2 = n2beg + k;
            const float4 z0 = *(const float4*)(ZH + n2 * 8);     // broadcast b128
            const float4 z1 = *(const float4*)(ZH + n2 * 8 + 4); // broadcast b128
            half2_t zp0 = __builtin_amdgcn_cvt_pkrtz(z0.x, z0.y);
            half2_t zp1 = __builtin_amdgcn_cvt_pkrtz(z0.z, z0.w);
            half2_t zp2 = __builtin_amdgcn_cvt_pkrtz(z1.x, z1.y);
            half2_t zp3 = __builtin_amdgcn_cvt_pkrtz(z1.z, z1.w);
            vfloat4 a;
            float t;
            t = hb4.x;
            t = __builtin_amdgcn_fdot2(zp0, u2h(w0.x), t, false);
            t = __builtin_amdgcn_fdot2(zp1, u2h(w0.y), t, false);
            t = __builtin_amdgcn_fdot2(zp2, u2h(w0.z), t, false);
            t = __builtin_amdgcn_fdot2(zp3, u2h(w0.w), t, false);
            a.x = t;
            t = hb4.y;
            t = __builtin_amdgcn_fdot2(zp0, u2h(w1.x), t, false);
            t = __builtin_amdgcn_fdot2(zp1, u2h(w1.y), t, false);
            t = __builtin_amdgcn_fdot2(zp2, u2h(w1.z), t, false);
            t = __builtin_amdgcn_fdot2(zp3, u2h(w1.w), t, false);
            a.y = t;
            t = hb4.z;
            t = __builtin_amdgcn_fdot2(zp0, u2h(w2.x), t, false);
            t = __builtin_amdgcn_fdot2(zp1, u2h(w2.y), t, false);
            t = __builtin_amdgcn_fdot2(zp2, u2h(w2.z), t, false);
            t = __builtin_amdgcn_fdot2(zp3, u2h(w2.w), t, false);
            a.z = t;
            t = hb4.w;
            t = __builtin_amdgcn_fdot2(zp0, u2h(w3.x), t, false);
            t = __builtin_amdgcn_fdot2(zp1, u2h(w3.y), t, false);
            t = __builtin_amdgcn_fdot2(zp2, u2h(w3.z), t, false);
            t = __builtin_amdgcn_fdot2(zp3, u2h(w3.w), t, false);
            a.w = t;
            __builtin_nontemporal_store(a, (vfloat4*)(oy + n2 * DIMD) + l);
        }
    }
}

// ---------------- fused fp32 fallback (v9, only if ws too small) ----------------
__launch_bounds__(256)
__global__ void sadapter_fused(
    const float* __restrict__ x,
    const float* __restrict__ W1,
    const float* __restrict__ b1,
    const float* __restrict__ conv1_w,
    const float* __restrict__ conv1_b,
    const float* __restrict__ cdc_w,
    const float* __restrict__ wc1,
    const float* __restrict__ wc2,
    const float* __restrict__ hist_w,
    const float* __restrict__ hist_b,
    float* __restrict__ out)
{
    __shared__ float smem[4608];
    float* TS  = smem;
    float* ZH  = smem;
    float* PS  = smem + 2048;
    float* WB2 = smem + 4096;
    const int tid = threadIdx.x;
    const float* xb   = x   + (size_t)blockIdx.x * IMGS;
    float*       outb = out + (size_t)blockIdx.x * IMGS;

    {
        float4 z4 = make_float4(0.f,0.f,0.f,0.f), o4 = make_float4(1.f,1.f,1.f,1.f);
        ((float4*)TS)[tid] = z4; ((float4*)TS)[tid+256] = z4;
        ((float4*)PS)[tid] = o4; ((float4*)PS)[tid+256] = o4;
    }
    if (tid < 64) {
        const float* c5 = cdc_w + tid * 5;
        float k0=c5[0],k1=c5[1],k2=c5[2],k3=c5[3],k4=c5[4];
        float kd = k0+k1+k2+k3+k4;
        float* wp = WB2 + tid*8;
        wp[0]=conv1_w[tid]+k2-0.7f*kd; wp[1]=k0; wp[2]=k1; wp[3]=k3; wp[4]=k4;
        wp[5]=wc1[tid]; wp[6]=wc2[tid]; wp[7]=0.f;
    }
    __syncthreads();
    if (tid < 196) {
        const float4* rowp = (const float4*)(xb + DIMD + tid * DIMD);
        float acc[8];
        #pragma unroll
        for (int c=0;c<8;++c) acc[c]=b1[c];
        #pragma unroll
        for (int blk=0; blk<6; ++blk) {
            float4 tv[8];
            #pragma unroll
            for (int u=0;u<8;++u) tv[u]=rowp[blk*8+u];
            #pragma unroll
            for (int c=0;c<8;++c) {
                const float* wrow = W1 + c*DIMD + blk*32;
                #pragma unroll
                for (int u=0;u<8;++u)
                    acc[c] += tv[u].x*wrow[u*4+0]+tv[u].y*wrow[u*4+1]
                            + tv[u].z*wrow[u*4+2]+tv[u].w*wrow[u*4+3];
            }
        }
        int h=tid/14, w=tid-h*14;
        float* tp = TS + (h+1)*16 + (w+1);
        #pragma unroll
        for (int c=0;c<8;++c) tp[c*256]=acc[c];
    } else if (tid >= 208) {
        ((float4*)outb)[tid-208] = ((const float4*)xb)[tid-208];
    }
    __syncthreads();
    if (tid < 196) {
        int h=tid/14, w=tid-h*14;
        const float* tp = TS + (h+1)*16 + (w+1);
        float zv[8];
        #pragma unroll
        for (int c=0;c<8;++c) zv[c]=conv1_b[c];
        #pragma unroll
        for (int i=0;i<8;++i) {
            float t0=tp[i*256], tu=tp[i*256-16], td=tp[i*256+16], tl=tp[i*256-1], tr=tp[i*256+1];
            #pragma unroll
            for (int c=0;c<8;++c) {
                const float* wp = WB2 + (c*8+i)*8;
                float4 wv = *(const float4*)wp;
                zv[c] += wv.x*t0 + wv.y*tu + wv.z*tl + wv.w*tr + wp[4]*td;
            }
        }
        float* pp = PS + (h+1)*16 + (w+1);
        #pragma unroll
        for (int c=0;c<8;++c) {
            float mu=0.f, ga=0.f;
            #pragma unroll
            for (int i=0;i<8;++i) {
                const float* wp = WB2 + (c*8+i)*8;
                mu += wp[5]*zv[i]; ga += wp[6]*zv[i];
            }
            float e = ga*(zv[c]-mu);
            pp[c*256] = __expf(-e*e);
        }
    }
    __syncthreads();
    const int l  = tid & 63;
    const int wv = tid >> 6;
    const float4 ha0 = *(const float4*)(hist_w + l * 8);
    const float4 ha1 = *(const float4*)(hist_w + l * 8 + 4);
    const float4 hb0 = *(const float4*)(hist_w + (l + 64) * 8);
    const float4 hb1 = *(const float4*)(hist_w + (l + 64) * 8 + 4);
    const float4 hc0 = *(const float4*)(hist_w + (l + 128) * 8);
    const float4 hc1 = *(const float4*)(hist_w + (l + 128) * 8 + 4);
    const float  ba  = hist_b[l];
    const float  bb  = hist_b[l + 64];
    const float  bc_ = hist_b[l + 128];
    if (tid < 196) {
        int h=tid/14, w=tid-h*14;
        const float* pb = PS + h*16 + w;
        #pragma unroll
        for (int c=0;c<8;++c) {
            const float* pr = pb + c*256;
            float s9 = pr[0]+pr[1]+pr[2]+pr[16]+pr[17]+pr[18]+pr[32]+pr[33]+pr[34];
            ZH[c*196+tid] = s9*(1.f/9.f);
        }
    }
    __syncthreads();
    {
        float* oy = outb + DIMD;
        const int n2beg = wv * 49;
        #pragma unroll 2
        for (int k = 0; k < 49; ++k) {
            const int n2 = n2beg + k;
            const float4 z0 = *(const float4*)(ZH + n2 * 8);
            const float4 z1 = *(const float4*)(ZH + n2 * 8 + 4);
            float a0 = ba + z0.x*ha0.x + z0.y*ha0.y + z0.z*ha0.z + z0.w*ha0.w
                          + z1.x*ha1.x + z1.y*ha1.y + z1.z*ha1.z + z1.w*ha1.w;
            float a1 = bb + z0.x*hb0.x + z0.y*hb0.y + z0.z*hb0.z + z0.w*hb0.w
                          + z1.x*hb1.x + z1.y*hb1.y + z1.z*hb1.z + z1.w*hb1.w;
            float a2 = bc_+ z0.x*hc0.x + z0.y*hc0.y + z0.z*hc0.z + z0.w*hc0.w
                          + z1.x*hc1.x + z1.y*hc1.y + z1.z*hc1.z + z1.w*hc1.w;
            float* orow = oy + n2 * DIMD;
            orow[l]       = a0;
            orow[l + 64]  = a1;
            orow[l + 128] = a2;
        }
    }
}

extern "C" void kernel_launch(void* const* d_in, const int* in_sizes, int n_in,
                              void* d_out, int out_size, void* d_ws, size_t ws_size,
                              hipStream_t stream)
{
    const float* x       = (const float*)d_in[0];
    const float* W1      = (const float*)d_in[1];
    const float* b1      = (const float*)d_in[2];
    const float* conv1_w = (const float*)d_in[3];
    const float* conv1_b = (const float*)d_in[4];
    const float* cdc_w   = (const float*)d_in[5];
    const float* wc1     = (const float*)d_in[6];
    const float* wc2     = (const float*)d_in[7];
    const float* hist_w  = (const float*)d_in[8];
    const float* hist_b  = (const float*)d_in[9];
    float* out = (float*)d_out;

    const size_t need = 2 * 768 * sizeof(unsigned);   // 6 KB
    if (ws_size >= need) {
        unsigned* wsA = (unsigned*)d_ws;
        unsigned* wsD = wsA + 768;
        k0_pack<<<3, 256, 0, stream>>>(W1, hist_w, wsA, wsD);
        sadapter_kernel<<<NIMG, 256, 0, stream>>>(
            x, b1, conv1_w, conv1_b, cdc_w, wc1, wc2, wsA, wsD, hist_b, out);
    } else {
        sadapter_fused<<<NIMG, 256, 0, stream>>>(
            x, W1, b1, conv1_w, conv1_b, cdc_w, wc1, wc2, hist_w, hist_b, out);
    }
}